// Round 1
// baseline (970.252 us; speedup 1.0000x reference)
//
#include <hip/hip_runtime.h>
#include <math.h>

// Problem constants (match reference)
#define NQ     16384
#define NN     32
#define F_INP  128
#define F_OUTP 256
#define KP     15
#define OD     42            // offset dim = 3*(K-1)
#define INV_EXTENT 0.5f      // 1/EXTENT, EXTENT = 2.0

#define E1 4                 // queries per block, kernel 1
#define E2 8                 // queries per block, kernel 2

// -------------------------------------------------------------------------
// Kernel 1: rigid KPConv producing offsets; writes deformed kernel points
// def_kp[q][15][3] (fp32) into workspace.
// -------------------------------------------------------------------------
__global__ __launch_bounds__(256, 2)
void kpconv_offsets(const float* __restrict__ query,
                    const float* __restrict__ support,
                    const int*   __restrict__ neighbors,
                    const float* __restrict__ features,
                    const float* __restrict__ kpoints,   // [15][3]
                    const float* __restrict__ dweight,   // [15][128][42]
                    const float* __restrict__ bias,      // [42]
                    float* __restrict__ defkp_out)       // [NQ][45]
{
    __shared__ float wf[E1][KP * F_INP];   // 30720 B
    __shared__ float w0s[E1][NN][KP];      // 7680 B
    __shared__ float kp_s[KP * 3];         // 180 B
    __shared__ int   nbr_s[E1][NN];        // 512 B
    __shared__ float dws[F_INP * OD];      // 21504 B  (one k-slice of dweight)

    const int tid   = threadIdx.x;
    const int qbase = blockIdx.x * E1;

    if (tid < KP * 3) kp_s[tid] = kpoints[tid];

    // Phase 1: gather rel (registers) + neighbor idx (LDS); threads 0..127
    float rx = 0.f, ry = 0.f, rz = 0.f;
    const int e = tid >> 5, n = tid & 31;
    if (tid < E1 * NN) {
        const int q   = qbase + e;
        const int idx = neighbors[q * NN + n];
        nbr_s[e][n] = idx;
        rx = support[idx * 3 + 0] - query[q * 3 + 0];
        ry = support[idx * 3 + 1] - query[q * 3 + 1];
        rz = support[idx * 3 + 2] - query[q * 3 + 2];
    }
    __syncthreads();

    // Phase 2: w0 = relu(1 - d/extent)
    if (tid < E1 * NN) {
        #pragma unroll
        for (int k = 0; k < KP; k++) {
            const float dx = rx - kp_s[k * 3 + 0];
            const float dy = ry - kp_s[k * 3 + 1];
            const float dz = rz - kp_s[k * 3 + 2];
            const float d  = sqrtf(dx * dx + dy * dy + dz * dz);
            const float w  = 1.0f - d * INV_EXTENT;
            w0s[e][n][k] = w > 0.0f ? w : 0.0f;
        }
    }
    __syncthreads();

    // Phase 3: wf0[e][k][f] = sum_n w0[e][n][k] * feat[nbr][f]
    {
        const int f    = tid & 127;
        const int half = tid >> 7;     // covers e = half*2 + {0,1}
        float acc[2][KP];
        #pragma unroll
        for (int ei = 0; ei < 2; ei++)
            #pragma unroll
            for (int k = 0; k < KP; k++) acc[ei][k] = 0.f;

        for (int ei = 0; ei < 2; ei++) {
            const int ee = half * 2 + ei;
            for (int nn2 = 0; nn2 < NN; nn2++) {
                const float v = features[nbr_s[ee][nn2] * F_INP + f];
                #pragma unroll
                for (int k = 0; k < KP; k++) acc[ei][k] += w0s[ee][nn2][k] * v;
            }
        }
        #pragma unroll
        for (int ei = 0; ei < 2; ei++) {
            const int ee = half * 2 + ei;
            #pragma unroll
            for (int k = 0; k < KP; k++) wf[ee][k * F_INP + f] = acc[ei][k];
        }
    }
    __syncthreads();

    // Phase 4: feat0[e][o] = sum_{k,f} wf0[e][k][f] * dweight[k][f][o] + bias[o]
    const int  ge  = tid / OD, go = tid % OD;
    const bool act = (tid < E1 * OD);   // 168 active threads
    float facc = act ? bias[go] : 0.f;

    for (int k = 0; k < KP; k++) {
        for (int i = tid; i < F_INP * OD; i += 256)
            dws[i] = dweight[k * F_INP * OD + i];
        __syncthreads();
        if (act) {
            const float* wfp = &wf[ge][k * F_INP];
            #pragma unroll 8
            for (int f = 0; f < F_INP; f++) facc += wfp[f] * dws[f * OD + go];
        }
        __syncthreads();
    }

    // Phase 5: def_kp = K_points + offsets (offset 0 for center point)
    if (act) {
        const int q = qbase + ge;
        defkp_out[q * 45 + 3 + go] = kp_s[3 + go] + facc;  // KP_EXTENT_CFG = 1.0
    }
    if (tid >= E1 * OD && tid < E1 * OD + 12) {
        const int j = tid - E1 * OD;       // 12 = 4 queries * 3 dims
        const int q = qbase + j / 3;
        defkp_out[q * 45 + (j % 3)] = kp_s[j % 3];
    }
}

// -------------------------------------------------------------------------
// Kernel 2: deformable KPConv -> out[q][256]
// -------------------------------------------------------------------------
__global__ __launch_bounds__(256, 2)
void kpconv_deform(const float* __restrict__ query,
                   const float* __restrict__ support,
                   const int*   __restrict__ neighbors,
                   const float* __restrict__ features,
                   const float* __restrict__ weight,   // [15][128][256]
                   const float* __restrict__ defkp,    // [NQ][45]
                   float* __restrict__ out)            // [NQ][256]
{
    __shared__ float wf[E2][KP * F_INP];   // 61440 B
    __shared__ float w1s[E2][NN][KP];      // 15360 B
    __shared__ float dk_s[E2][45];         // 1440 B
    __shared__ int   nbr_s[E2][NN];        // 1024 B

    const int tid   = threadIdx.x;
    const int qbase = blockIdx.x * E2;

    for (int i = tid; i < E2 * 45; i += 256)
        dk_s[i / 45][i % 45] = defkp[qbase * 45 + i];

    // Phase 1: gather (all 256 threads: e<8, n<32)
    const int e = tid >> 5, n = tid & 31;
    const int q   = qbase + e;
    const int idx = neighbors[q * NN + n];
    nbr_s[e][n] = idx;
    const float rx = support[idx * 3 + 0] - query[q * 3 + 0];
    const float ry = support[idx * 3 + 1] - query[q * 3 + 1];
    const float rz = support[idx * 3 + 2] - query[q * 3 + 2];
    __syncthreads();

    // Phase 2: w1 from deformed kernel points
    #pragma unroll
    for (int k = 0; k < KP; k++) {
        const float dx = rx - dk_s[e][k * 3 + 0];
        const float dy = ry - dk_s[e][k * 3 + 1];
        const float dz = rz - dk_s[e][k * 3 + 2];
        const float d  = sqrtf(dx * dx + dy * dy + dz * dz);
        const float w  = 1.0f - d * INV_EXTENT;
        w1s[e][n][k] = w > 0.0f ? w : 0.0f;
    }
    __syncthreads();

    // Phase 3: wf1[e][k][f] = sum_n w1[e][n][k] * feat[nbr][f]
    {
        const int f    = tid & 127;
        const int half = tid >> 7;          // covers e = half*4 + {0..3}
        float acc[4][KP];
        #pragma unroll
        for (int ei = 0; ei < 4; ei++)
            #pragma unroll
            for (int k = 0; k < KP; k++) acc[ei][k] = 0.f;

        for (int ei = 0; ei < 4; ei++) {
            const int ee = half * 4 + ei;
            for (int nn2 = 0; nn2 < NN; nn2++) {
                const float v = features[nbr_s[ee][nn2] * F_INP + f];
                #pragma unroll
                for (int k = 0; k < KP; k++) acc[ei][k] += w1s[ee][nn2][k] * v;
            }
        }
        #pragma unroll
        for (int ei = 0; ei < 4; ei++) {
            const int ee = half * 4 + ei;
            #pragma unroll
            for (int k = 0; k < KP; k++) wf[ee][k * F_INP + f] = acc[ei][k];
        }
    }
    __syncthreads();

    // Phase 4: GEMM out[e][o] = sum_kf wf[e][kf] * weight[kf][o],  o = tid.
    // Each weight value is read exactly once per block (coalesced);
    // wf read via float4 LDS broadcasts.
    float acc[E2];
    #pragma unroll
    for (int ee = 0; ee < E2; ee++) acc[ee] = 0.f;

    const float* wbase = weight + tid;
    for (int kf4 = 0; kf4 < (KP * F_INP) / 4; kf4++) {
        float4 wv[E2];
        #pragma unroll
        for (int ee = 0; ee < E2; ee++)
            wv[ee] = *(const float4*)&wf[ee][kf4 * 4];
        const float* wp = wbase + (kf4 * 4) * F_OUTP;
        const float b0 = wp[0];
        const float b1 = wp[F_OUTP];
        const float b2 = wp[2 * F_OUTP];
        const float b3 = wp[3 * F_OUTP];
        #pragma unroll
        for (int ee = 0; ee < E2; ee++)
            acc[ee] += wv[ee].x * b0 + wv[ee].y * b1 + wv[ee].z * b2 + wv[ee].w * b3;
    }

    #pragma unroll
    for (int ee = 0; ee < E2; ee++)
        out[(qbase + ee) * F_OUTP + tid] = acc[ee];
}

// -------------------------------------------------------------------------
extern "C" void kernel_launch(void* const* d_in, const int* in_sizes, int n_in,
                              void* d_out, int out_size, void* d_ws, size_t ws_size,
                              hipStream_t stream) {
    const float* query     = (const float*)d_in[0];   // [16384][3]
    const float* support   = (const float*)d_in[1];   // [16384][3]
    const int*   neighbors = (const int*)  d_in[2];   // [16384][32]
    const float* features  = (const float*)d_in[3];   // [16384][128]
    const float* kpoints   = (const float*)d_in[4];   // [15][3]
    const float* weight    = (const float*)d_in[5];   // [15][128][256]
    const float* dweight   = (const float*)d_in[6];   // [15][128][42]
    const float* bias      = (const float*)d_in[7];   // [42]
    float*       out       = (float*)d_out;           // [16384][256]

    float* defkp = (float*)d_ws;                      // [16384][45] = 2.95 MB

    kpconv_offsets<<<NQ / E1, 256, 0, stream>>>(query, support, neighbors,
                                                features, kpoints, dweight,
                                                bias, defkp);
    kpconv_deform<<<NQ / E2, 256, 0, stream>>>(query, support, neighbors,
                                               features, weight, defkp, out);
}